// Round 2
// baseline (342.984 us; speedup 1.0000x reference)
//
#include <hip/hip_runtime.h>

// Problem constants: x:(B,T,2P) f32, resolution:(B,T,2) f32, origin:(B,T,2) f32
// -> out:(B,T,H,W,P) f32 one-hot raster grid.
#define BB 32
#define TT 10
#define PP 25
#define HH 100
#define WW 100

// Dense-write formulation: instead of memset(320MB) + sparse scatter (8000
// stores with partial-line RMW), write every output element exactly once:
//   out[bt][h][w][p] = (cell[bt][p] == h*W + w) ? 1 : 0
// where cell[bt][p] is the (row*W+col) target of point (bt,p), or -1 if OOB.
// One dispatch, pure coalesced float4 streaming stores at memset-level BW.
//
// Per bt: 100*100*25 = 250,000 floats = 62,500 float4 (16B-aligned: bt stride
// is 1,000,000 B, and e*4 is a multiple of 16).
__global__ __launch_bounds__(256) void raster_dense_kernel(
        const float* __restrict__ x,
        const float* __restrict__ resolution,
        const float* __restrict__ origin,
        float* __restrict__ out) {
    const int bt  = blockIdx.y;   // 0..319
    const int tid = threadIdx.x;

    // Stage the 25 target cells for this (b,t) in LDS.
    __shared__ int cell[PP];
    if (tid < PP) {
        const float px = x[bt * (2 * PP) + 2 * tid];      // x-coord
        const float py = x[bt * (2 * PP) + 2 * tid + 1];  // y-coord
        const float r0 = resolution[bt * 2 + 0];          // row uses res[...,0]
        const float r1 = resolution[bt * 2 + 1];          // col uses res[...,1]
        const float o0 = origin[bt * 2 + 0];
        const float o1 = origin[bt * 2 + 1];
        // jnp .astype(int32) truncates toward zero, same as C cast.
        const int row = (int)(py / r0 + o0);
        const int col = (int)(px / r1 + o1);
        cell[tid] = (row >= 0 && row < HH && col >= 0 && col < WW)
                        ? (row * WW + col) : -1;
    }
    __syncthreads();

    const int i4 = blockIdx.x * 256 + tid;   // float4 index within this bt
    const int N4 = (HH * WW * PP) / 4;       // 62,500
    if (i4 >= N4) return;

    const int e = i4 * 4;                    // element index within bt
    int p  = e % PP;                         // channel
    int hw = e / PP;                         // h*W + w cell index (0..9999)

    float vals[4];
#pragma unroll
    for (int j = 0; j < 4; ++j) {
        vals[j] = (cell[p] == hw) ? 1.0f : 0.0f;
        if (++p == PP) { p = 0; ++hw; }
    }

    float4 v = make_float4(vals[0], vals[1], vals[2], vals[3]);
    *reinterpret_cast<float4*>(out + (size_t)bt * (HH * WW * PP) + e) = v;
}

extern "C" void kernel_launch(void* const* d_in, const int* in_sizes, int n_in,
                              void* d_out, int out_size, void* d_ws, size_t ws_size,
                              hipStream_t stream) {
    const float* x          = (const float*)d_in[0];
    const float* resolution = (const float*)d_in[1];
    const float* origin     = (const float*)d_in[2];
    float* out = (float*)d_out;

    // Single fused dispatch: no memset needed — every logical output element
    // is written exactly once (poisoned bytes in the logical region are all
    // overwritten).
    const int N4 = (HH * WW * PP) / 4;               // 62,500 float4 per bt
    dim3 grid((N4 + 255) / 256, BB * TT);            // (245, 320)
    raster_dense_kernel<<<grid, 256, 0, stream>>>(x, resolution, origin, out);
}

// Round 4
// 317.517 us; speedup vs baseline: 1.0802x; 1.0802x over previous
//
#include <hip/hip_runtime.h>

// Problem constants: x:(B,T,2P) f32, resolution:(B,T,2) f32, origin:(B,T,2) f32
// -> out:(B,T,H,W,P) f32 one-hot raster grid.
#define BB 32
#define TT 10
#define PP 25
#define HH 100
#define WW 100

#define N4_PER_BT ((HH * WW * PP) / 4)   // 62,500 float4 per (b,t)
#define BLOCKS_PER_BT 8                  // 2560 blocks total, ~125 KB payload each

// clang ext-vector for __builtin_nontemporal_store (HIP's float4 class type
// is rejected by the builtin; this lowers to the same global_store_dwordx4).
typedef float f32x4 __attribute__((ext_vector_type(4)));

// Dense-write formulation, memset-structured: out[bt][h][w][p] =
// (cell[bt][p] == h*W+w).  One dispatch; every element written exactly once.
// Round-2 lesson: 4 KB/block payload is overhead-dominated — grid-stride with
// ~125 KB/block like fillBufferAligned does.
__global__ __launch_bounds__(256) void raster_dense_kernel(
        const float* __restrict__ x,
        const float* __restrict__ resolution,
        const float* __restrict__ origin,
        float* __restrict__ out) {
    const int bt  = blockIdx.y;   // 0..319
    const int tid = threadIdx.x;

    // Stage the 25 target cells for this (b,t) in LDS (banks 0..24, conflict-free).
    __shared__ int cell[PP];
    if (tid < PP) {
        const float px = x[bt * (2 * PP) + 2 * tid];      // x-coord
        const float py = x[bt * (2 * PP) + 2 * tid + 1];  // y-coord
        const float r0 = resolution[bt * 2 + 0];          // row uses res[...,0]
        const float r1 = resolution[bt * 2 + 1];          // col uses res[...,1]
        const float o0 = origin[bt * 2 + 0];
        const float o1 = origin[bt * 2 + 1];
        // jnp .astype(int32) truncates toward zero, same as C cast.
        const int row = (int)(py / r0 + o0);
        const int col = (int)(px / r1 + o1);
        cell[tid] = (row >= 0 && row < HH && col >= 0 && col < WW)
                        ? (row * WW + col) : -1;
    }
    __syncthreads();

    float* const base = out + (size_t)bt * (HH * WW * PP);

    // Grid-stride over this bt's 62,500 float4s: ~31 iterations/thread,
    // consecutive lanes -> consecutive 16B, 1 KiB per wave-store.
    for (int i4 = blockIdx.x * 256 + tid; i4 < N4_PER_BT;
         i4 += BLOCKS_PER_BT * 256) {
        const int e  = i4 * 4;          // element index within bt
        int hw = e / PP;                // cell index 0..9999 (magic-mul div)
        int p  = e - hw * PP;           // channel 0..24

        f32x4 v;
#pragma unroll
        for (int j = 0; j < 4; ++j) {
            v[j] = (cell[p] == hw) ? 1.0f : 0.0f;
            if (++p == PP) { p = 0; ++hw; }
        }

        __builtin_nontemporal_store(
            v, reinterpret_cast<f32x4*>(base + e));
    }
}

extern "C" void kernel_launch(void* const* d_in, const int* in_sizes, int n_in,
                              void* d_out, int out_size, void* d_ws, size_t ws_size,
                              hipStream_t stream) {
    const float* x          = (const float*)d_in[0];
    const float* resolution = (const float*)d_in[1];
    const float* origin     = (const float*)d_in[2];
    float* out = (float*)d_out;

    // Single fused dispatch: no memset needed — every logical output element
    // is written exactly once (all poisoned bytes in the logical region are
    // overwritten).
    dim3 grid(BLOCKS_PER_BT, BB * TT);   // (8, 320) = 2560 blocks
    raster_dense_kernel<<<grid, 256, 0, stream>>>(x, resolution, origin, out);
}